// Round 2
// baseline (650.850 us; speedup 1.0000x reference)
//
#include <hip/hip_runtime.h>

// PositionAwareAttention: S=8192, B=64, D=512, A=256, all fp32 I/O.
// Fused flash-style: x read from HBM exactly once (1.07 GB).
//   k0: Wx fp32 -> fp16 (ws)
//   k1: whb[b,a] = h[b,:].Wh[a,:] + bx[a] (ws)
//   k2: per (b, 64-row s-tile): wx = x.W^T via f16 MFMA. x staged to a
//       64 KiB XOR-swizzled fp16 LDS tile (persists for the weighted sum);
//       W fragments read directly from global (L1/L2-resident, no LDS).
//       Epilogue: tanh + Wt reduce -> tile softmax partial (m, l, acc[512]).
//   k3: combine partials over 128 tiles per b -> out[b,d].
// bt omitted: softmax is shift-invariant.
// LDS = 67.3 KiB -> 2 blocks/CU (R1 fix: was 140 KiB -> 1 block/CU).

#define S_DIM 8192
#define B_DIM 64
#define D_DIM 512
#define A_DIM 256
#define BM 64
#define BK 64
#define NCHUNK 8              // D / BK
#define NTILES 128            // S / BM

typedef _Float16 half8 __attribute__((ext_vector_type(8)));
typedef float f32x4 __attribute__((ext_vector_type(4)));

// LDS: xs[64][512] f16 swizzled (65536 B) + scorep[256] + pbuf[64] + whb_s[256] + wt_s[256]
#define SMEM_MAIN (65536 + (256 + 64 + 256 + 256) * 4)

__device__ __forceinline__ float tanh_fast(float x) {
  // tanh(x) = 1 - 2/(exp(2x)+1); exp->inf/0 saturates correctly to +/-1
  float e = __expf(2.0f * x);
  return 1.0f - 2.0f * __builtin_amdgcn_rcpf(e + 1.0f);
}

__global__ void __launch_bounds__(256)
convw_kernel(const float* __restrict__ Wx, _Float16* __restrict__ Wf) {
  const int idx = (blockIdx.x * 256 + threadIdx.x) * 8;
  f32x4 a = *(const f32x4*)(Wx + idx);
  f32x4 b = *(const f32x4*)(Wx + idx + 4);
  half8 hx;
#pragma unroll
  for (int i = 0; i < 4; ++i) { hx[i] = (_Float16)a[i]; hx[4 + i] = (_Float16)b[i]; }
  *(half8*)(Wf + idx) = hx;
}

__global__ void __launch_bounds__(256)
whb_kernel(const float* __restrict__ h, const float* __restrict__ Wh,
           const float* __restrict__ bx, float* __restrict__ whb) {
  __shared__ float hs[D_DIM];
  const int b = blockIdx.x, tid = threadIdx.x;
  hs[tid] = h[b * D_DIM + tid];
  hs[tid + 256] = h[b * D_DIM + 256 + tid];
  __syncthreads();
  const int g = tid >> 4, i = tid & 15;  // 16 lanes cooperate on one a-row
  for (int pass = 0; pass < 16; ++pass) {
    const int a = pass * 16 + g;
    const f32x4* wrow = (const f32x4*)(Wh + (size_t)a * D_DIM);
    float dot = 0.f;
#pragma unroll
    for (int k = 0; k < 8; ++k) {
      f32x4 wv = wrow[i + k * 16];
      f32x4 hv = *(const f32x4*)(hs + (i + k * 16) * 4);
      dot += wv[0] * hv[0] + wv[1] * hv[1] + wv[2] * hv[2] + wv[3] * hv[3];
    }
#pragma unroll
    for (int mask = 1; mask < 16; mask <<= 1) dot += __shfl_xor(dot, mask, 64);
    if (i == 0) whb[b * A_DIM + a] = dot + bx[a];
  }
}

__global__ void __launch_bounds__(512, 4)
paa_main(const float* __restrict__ x, const _Float16* __restrict__ Wf,
         const float* __restrict__ whb, const float* __restrict__ Wt,
         float* __restrict__ m_arr, float* __restrict__ l_arr,
         float* __restrict__ acc_arr) {
  extern __shared__ char smem[];
  _Float16* xs = (_Float16*)smem;                 // [64][512] f16, 16B-slot XOR swizzle
  float* scorep = (float*)(smem + 65536);         // [4][BM]
  float* pbuf = scorep + 4 * BM;                  // [BM]
  float* whb_s = pbuf + BM;                       // [A]
  float* wt_s = whb_s + A_DIM;                    // [A]

  const int tid = threadIdx.x;
  const int b = blockIdx.y;
  const int tile = blockIdx.x;
  const int s0 = tile * BM;

  if (tid < A_DIM) { whb_s[tid] = whb[b * A_DIM + tid]; wt_s[tid] = Wt[tid]; }

  // x staging map: row xr = tid/8, 8-float segment xj = tid%8
  const int xr = tid >> 3, xj = tid & 7;
  const float* xg = x + (size_t)(s0 + xr) * (B_DIM * D_DIM) + b * D_DIM + xj * 8;
  const int xj_sw = xj ^ (xr & 7);                // swizzled 16B slot within chunk window
  _Float16* xw = xs + xr * D_DIM + xj_sw * 8;

  f32x4 xre0, xre1;
  auto load_x = [&](int c) {
    const float* p = xg + c * BK;
    xre0 = *(const f32x4*)(p);
    xre1 = *(const f32x4*)(p + 4);
  };
  auto write_x = [&](int c) {
    half8 hx;
#pragma unroll
    for (int i = 0; i < 4; ++i) { hx[i] = (_Float16)xre0[i]; hx[4 + i] = (_Float16)xre1[i]; }
    *(half8*)(xw + c * BK) = hx;
  };

  f32x4 acc[2][4];
#pragma unroll
  for (int i = 0; i < 2; ++i)
#pragma unroll
    for (int j = 0; j < 4; ++j) acc[i][j] = (f32x4){0.f, 0.f, 0.f, 0.f};

  const int lane = tid & 63;
  const int wv = tid >> 6;
  const int wm = wv >> 2, wn = wv & 3;           // wave tile: rows wm*32+.., cols wn*64+..
  const int fr = lane & 15, fg = lane >> 4;
  const int a_row0 = wm * 32 + fr;               // and a_row0+16: same (&7) -> same swizzle key
  const int akey = a_row0 & 7;
  const _Float16* wg = Wf + (size_t)(wn * 64 + fr) * D_DIM + fg * 8;  // B-frag base (global)

  load_x(0);
  write_x(0);
  __syncthreads();

  for (int c = 0; c < NCHUNK; ++c) {
    if (c + 1 < NCHUNK) load_x(c + 1);           // HBM loads in flight across MFMAs
    const _Float16* wc = wg + c * BK;
#pragma unroll
    for (int kk = 0; kk < 2; ++kk) {
      const int slot = (c * 8 + kk * 4 + fg) ^ akey;
      half8 af0 = *(const half8*)(xs + a_row0 * D_DIM + slot * 8);
      half8 af1 = *(const half8*)(xs + (a_row0 + 16) * D_DIM + slot * 8);
      half8 bf0 = *(const half8*)(wc + kk * 32);
      half8 bf1 = *(const half8*)(wc + kk * 32 + 16 * D_DIM);
      half8 bf2 = *(const half8*)(wc + kk * 32 + 32 * D_DIM);
      half8 bf3 = *(const half8*)(wc + kk * 32 + 48 * D_DIM);
      acc[0][0] = __builtin_amdgcn_mfma_f32_16x16x32_f16(af0, bf0, acc[0][0], 0, 0, 0);
      acc[0][1] = __builtin_amdgcn_mfma_f32_16x16x32_f16(af0, bf1, acc[0][1], 0, 0, 0);
      acc[0][2] = __builtin_amdgcn_mfma_f32_16x16x32_f16(af0, bf2, acc[0][2], 0, 0, 0);
      acc[0][3] = __builtin_amdgcn_mfma_f32_16x16x32_f16(af0, bf3, acc[0][3], 0, 0, 0);
      acc[1][0] = __builtin_amdgcn_mfma_f32_16x16x32_f16(af1, bf0, acc[1][0], 0, 0, 0);
      acc[1][1] = __builtin_amdgcn_mfma_f32_16x16x32_f16(af1, bf1, acc[1][1], 0, 0, 0);
      acc[1][2] = __builtin_amdgcn_mfma_f32_16x16x32_f16(af1, bf2, acc[1][2], 0, 0, 0);
      acc[1][3] = __builtin_amdgcn_mfma_f32_16x16x32_f16(af1, bf3, acc[1][3], 0, 0, 0);
    }
    if (c + 1 < NCHUNK) write_x(c + 1);          // region c+1: no race with reads of region c
    __syncthreads();
  }

  // epilogue: score[s] = sum_a Wt[a] * tanh(wx + whb)  (C frag: row=fg*4+reg, col=fr)
  float part[2][4];
#pragma unroll
  for (int mi = 0; mi < 2; ++mi)
#pragma unroll
    for (int r = 0; r < 4; ++r) part[mi][r] = 0.f;
#pragma unroll
  for (int ni = 0; ni < 4; ++ni) {
    const int a_idx = wn * 64 + ni * 16 + fr;
    const float wt_a = wt_s[a_idx];
    const float whb_a = whb_s[a_idx];
#pragma unroll
    for (int mi = 0; mi < 2; ++mi)
#pragma unroll
      for (int r = 0; r < 4; ++r)
        part[mi][r] += wt_a * tanh_fast(acc[mi][ni][r] + whb_a);
  }
#pragma unroll
  for (int mask = 1; mask < 16; mask <<= 1) {
#pragma unroll
    for (int mi = 0; mi < 2; ++mi)
#pragma unroll
      for (int r = 0; r < 4; ++r) part[mi][r] += __shfl_xor(part[mi][r], mask, 64);
  }
  if (fr == 0) {
#pragma unroll
    for (int mi = 0; mi < 2; ++mi)
#pragma unroll
      for (int r = 0; r < 4; ++r)
        scorep[wn * BM + wm * 32 + mi * 16 + fg * 4 + r] = part[mi][r];
  }
  __syncthreads();

  // tile-local softmax partial (wave 0 only: tid<64)
  if (tid < BM) {
    float sv = scorep[tid] + scorep[BM + tid] + scorep[2 * BM + tid] + scorep[3 * BM + tid];
    float m = sv;
#pragma unroll
    for (int mask = 1; mask < 64; mask <<= 1) m = fmaxf(m, __shfl_xor(m, mask, 64));
    float p = __expf(sv - m);
    float lsum = p;
#pragma unroll
    for (int mask = 1; mask < 64; mask <<= 1) lsum += __shfl_xor(lsum, mask, 64);
    pbuf[tid] = p;
    if (tid == 0) {
      m_arr[b * NTILES + tile] = m;
      l_arr[b * NTILES + tile] = lsum;
    }
  }
  __syncthreads();

  // acc[d] = sum_r p[r] * x[r][d], from the resident swizzled fp16 tile
  {
    float pacc[8];
#pragma unroll
    for (int j = 0; j < 8; ++j) pacc[j] = 0.f;
#pragma unroll
    for (int r = 0; r < 8; ++r) {
      const int row = wv * 8 + r;
      const float pr = pbuf[row];
      half8 v = *(const half8*)(xs + row * D_DIM + ((lane ^ (row & 7)) * 8));
#pragma unroll
      for (int j = 0; j < 8; ++j) pacc[j] += pr * (float)v[j];
    }
    __syncthreads();                 // all xs reads done before reuse as red buffer
    float* red = (float*)xs;         // 8*512*4 = 16 KiB inside xs
#pragma unroll
    for (int j = 0; j < 8; ++j) red[wv * 512 + lane * 8 + j] = pacc[j];
    __syncthreads();
    float s = 0.f;
#pragma unroll
    for (int w2 = 0; w2 < 8; ++w2) s += red[w2 * 512 + tid];
    acc_arr[((size_t)(b * NTILES + tile)) * D_DIM + tid] = s;
  }
}

__global__ void __launch_bounds__(512)
combine_kernel(const float* __restrict__ m_arr, const float* __restrict__ l_arr,
               const float* __restrict__ acc_arr, float* __restrict__ out) {
  __shared__ float ml[NTILES], ls[NTILES], wl[NTILES];
  const int b = blockIdx.x, tid = threadIdx.x;
  if (tid < NTILES) {
    ml[tid] = m_arr[b * NTILES + tid];
    ls[tid] = l_arr[b * NTILES + tid];
  }
  __syncthreads();
  float M = -1e30f;
  for (int i = 0; i < NTILES; ++i) M = fmaxf(M, ml[i]);
  if (tid < NTILES) wl[tid] = __expf(ml[tid] - M);
  __syncthreads();
  float L = 0.f;
  for (int i = 0; i < NTILES; ++i) L += wl[i] * ls[i];
  float sum = 0.f;
  const size_t base = (size_t)b * NTILES * D_DIM + tid;
  for (int i = 0; i < NTILES; ++i) sum += wl[i] * acc_arr[base + (size_t)i * D_DIM];
  out[b * D_DIM + tid] = sum / L;
}

extern "C" void kernel_launch(void* const* d_in, const int* in_sizes, int n_in,
                              void* d_out, int out_size, void* d_ws, size_t ws_size,
                              hipStream_t stream) {
  const float* x = (const float*)d_in[0];
  const float* h = (const float*)d_in[1];
  const float* Wx = (const float*)d_in[2];
  const float* bx = (const float*)d_in[3];
  const float* Wh = (const float*)d_in[4];
  const float* Wt = (const float*)d_in[5];
  // d_in[6] = bt: unused (softmax shift-invariant)

  char* ws = (char*)d_ws;
  _Float16* Wf = (_Float16*)ws;                               // 262144 B
  float* whb = (float*)(ws + 262144);                         // 65536 B
  float* m_arr = (float*)(ws + 262144 + 65536);               // 32768 B
  float* l_arr = (float*)(ws + 262144 + 65536 + 32768);       // 32768 B
  float* acc_arr = (float*)(ws + 262144 + 65536 + 65536);     // 16.8 MB

  hipFuncSetAttribute(reinterpret_cast<const void*>(paa_main),
                      hipFuncAttributeMaxDynamicSharedMemorySize, SMEM_MAIN);

  hipLaunchKernelGGL(convw_kernel, dim3(64), dim3(256), 0, stream, Wx, Wf);
  hipLaunchKernelGGL(whb_kernel, dim3(B_DIM), dim3(256), 0, stream, h, Wh, bx, whb);
  hipLaunchKernelGGL(paa_main, dim3(NTILES, B_DIM), dim3(512), SMEM_MAIN, stream,
                     x, Wf, whb, Wt, m_arr, l_arr, acc_arr);
  hipLaunchKernelGGL(combine_kernel, dim3(B_DIM), dim3(512), 0, stream,
                     m_arr, l_arr, acc_arr, (float*)d_out);
}

// Round 3
// 621.013 us; speedup vs baseline: 1.0480x; 1.0480x over previous
//
#include <hip/hip_runtime.h>

// PositionAwareAttention: S=8192, B=64, D=512, A=256, all fp32 I/O.
// Fused flash-style: x read from HBM exactly once (1.07 GB).
//   k0: Wx fp32 -> fp16 (ws)
//   k1: whb[b,a] = h[b,:].Wh[a,:] + bx[a] (ws)
//   k2: per (b, 64-row s-tile): wx = x.W^T via f16 MFMA. x staged to a
//       64 KiB XOR-swizzled fp16 LDS tile in ONE shot (16 dwordx4/thread,
//       single barrier); K-loop has NO barriers -> no vmcnt(0) drains.
//       W fragments stream from global (L2-resident). Epilogue: tanh + Wt
//       reduce -> tile softmax partial (m, l, acc[512]).
//   k3: combine partials over 128 tiles per b -> out[b,d].
// bt omitted: softmax is shift-invariant.

#define S_DIM 8192
#define B_DIM 64
#define D_DIM 512
#define A_DIM 256
#define BM 64
#define BK 64
#define NCHUNK 8              // D / BK
#define NTILES 128            // S / BM

typedef _Float16 half8 __attribute__((ext_vector_type(8)));
typedef float f32x4 __attribute__((ext_vector_type(4)));

// LDS: xs[64][512] f16 swizzled (65536 B) + scorep[256] + pbuf[64] + whb_s[256] + wt_s[256]
#define SMEM_MAIN (65536 + (256 + 64 + 256 + 256) * 4)

__device__ __forceinline__ float tanh_fast(float x) {
  // tanh(x) = 1 - 2/(exp(2x)+1); exp->inf/0 saturates correctly to +/-1
  float e = __expf(2.0f * x);
  return 1.0f - 2.0f * __builtin_amdgcn_rcpf(e + 1.0f);
}

__global__ void __launch_bounds__(256)
convw_kernel(const float* __restrict__ Wx, _Float16* __restrict__ Wf) {
  const int idx = (blockIdx.x * 256 + threadIdx.x) * 8;
  f32x4 a = *(const f32x4*)(Wx + idx);
  f32x4 b = *(const f32x4*)(Wx + idx + 4);
  half8 hx;
#pragma unroll
  for (int i = 0; i < 4; ++i) { hx[i] = (_Float16)a[i]; hx[4 + i] = (_Float16)b[i]; }
  *(half8*)(Wf + idx) = hx;
}

__global__ void __launch_bounds__(256)
whb_kernel(const float* __restrict__ h, const float* __restrict__ Wh,
           const float* __restrict__ bx, float* __restrict__ whb) {
  __shared__ float hs[D_DIM];
  const int b = blockIdx.x, tid = threadIdx.x;
  hs[tid] = h[b * D_DIM + tid];
  hs[tid + 256] = h[b * D_DIM + 256 + tid];
  __syncthreads();
  const int g = tid >> 4, i = tid & 15;  // 16 lanes cooperate on one a-row
  for (int pass = 0; pass < 16; ++pass) {
    const int a = pass * 16 + g;
    const f32x4* wrow = (const f32x4*)(Wh + (size_t)a * D_DIM);
    float dot = 0.f;
#pragma unroll
    for (int k = 0; k < 8; ++k) {
      f32x4 wv = wrow[i + k * 16];
      f32x4 hv = *(const f32x4*)(hs + (i + k * 16) * 4);
      dot += wv[0] * hv[0] + wv[1] * hv[1] + wv[2] * hv[2] + wv[3] * hv[3];
    }
#pragma unroll
    for (int mask = 1; mask < 16; mask <<= 1) dot += __shfl_xor(dot, mask, 64);
    if (i == 0) whb[b * A_DIM + a] = dot + bx[a];
  }
}

__global__ void __launch_bounds__(512, 4)
paa_main(const float* __restrict__ x, const _Float16* __restrict__ Wf,
         const float* __restrict__ whb, const float* __restrict__ Wt,
         float* __restrict__ m_arr, float* __restrict__ l_arr,
         float* __restrict__ acc_arr) {
  extern __shared__ char smem[];
  _Float16* xs = (_Float16*)smem;                 // [64][512] f16, 16B-slot XOR swizzle
  float* scorep = (float*)(smem + 65536);         // [4][BM]
  float* pbuf = scorep + 4 * BM;                  // [BM]
  float* whb_s = pbuf + BM;                       // [A]
  float* wt_s = whb_s + A_DIM;                    // [A]

  const int tid = threadIdx.x;
  const int b = blockIdx.y;
  const int tile = blockIdx.x;
  const int s0 = tile * BM;

  if (tid < A_DIM) { whb_s[tid] = whb[b * A_DIM + tid]; wt_s[tid] = Wt[tid]; }

  // x staging map: row xr = tid/8, 8-float segment xj = tid%8
  const int xr = tid >> 3, xj = tid & 7;
  const float* xg = x + (size_t)(s0 + xr) * (B_DIM * D_DIM) + b * D_DIM + xj * 8;
  const int xj_sw = xj ^ (xr & 7);                // swizzled 16B slot within chunk window
  _Float16* xw = xs + xr * D_DIM + xj_sw * 8;

  // ---- one-shot staging: all 16 dwordx4 loads in flight, then convert+write, ONE barrier
  f32x4 xa[NCHUNK], xb[NCHUNK];
#pragma unroll
  for (int c = 0; c < NCHUNK; ++c) {
    const float* p = xg + c * BK;
    xa[c] = *(const f32x4*)(p);
    xb[c] = *(const f32x4*)(p + 4);
  }
#pragma unroll
  for (int c = 0; c < NCHUNK; ++c) {
    half8 hx;
#pragma unroll
    for (int i = 0; i < 4; ++i) { hx[i] = (_Float16)xa[c][i]; hx[4 + i] = (_Float16)xb[c][i]; }
    *(half8*)(xw + c * BK) = hx;
  }
  __syncthreads();

  f32x4 acc[2][4];
#pragma unroll
  for (int i = 0; i < 2; ++i)
#pragma unroll
    for (int j = 0; j < 4; ++j) acc[i][j] = (f32x4){0.f, 0.f, 0.f, 0.f};

  const int lane = tid & 63;
  const int wv = tid >> 6;
  const int wm = wv >> 2, wn = wv & 3;           // wave tile: rows wm*32+.., cols wn*64+..
  const int fr = lane & 15, fg = lane >> 4;
  const int a_row0 = wm * 32 + fr;               // and a_row0+16: same (&7) -> same swizzle key
  const int akey = a_row0 & 7;
  const _Float16* wg = Wf + (size_t)(wn * 64 + fr) * D_DIM + fg * 8;  // B-frag base (global)

  // ---- K-loop: NO barriers, no fences. Compiler free to pipeline global W loads.
#pragma unroll
  for (int c = 0; c < NCHUNK; ++c) {
    const _Float16* wc = wg + c * BK;
#pragma unroll
    for (int kk = 0; kk < 2; ++kk) {
      const int slot = (c * 8 + kk * 4 + fg) ^ akey;
      half8 af0 = *(const half8*)(xs + a_row0 * D_DIM + slot * 8);
      half8 af1 = *(const half8*)(xs + (a_row0 + 16) * D_DIM + slot * 8);
      half8 bf0 = *(const half8*)(wc + kk * 32);
      half8 bf1 = *(const half8*)(wc + kk * 32 + 16 * D_DIM);
      half8 bf2 = *(const half8*)(wc + kk * 32 + 32 * D_DIM);
      half8 bf3 = *(const half8*)(wc + kk * 32 + 48 * D_DIM);
      acc[0][0] = __builtin_amdgcn_mfma_f32_16x16x32_f16(af0, bf0, acc[0][0], 0, 0, 0);
      acc[0][1] = __builtin_amdgcn_mfma_f32_16x16x32_f16(af0, bf1, acc[0][1], 0, 0, 0);
      acc[0][2] = __builtin_amdgcn_mfma_f32_16x16x32_f16(af0, bf2, acc[0][2], 0, 0, 0);
      acc[0][3] = __builtin_amdgcn_mfma_f32_16x16x32_f16(af0, bf3, acc[0][3], 0, 0, 0);
      acc[1][0] = __builtin_amdgcn_mfma_f32_16x16x32_f16(af1, bf0, acc[1][0], 0, 0, 0);
      acc[1][1] = __builtin_amdgcn_mfma_f32_16x16x32_f16(af1, bf1, acc[1][1], 0, 0, 0);
      acc[1][2] = __builtin_amdgcn_mfma_f32_16x16x32_f16(af1, bf2, acc[1][2], 0, 0, 0);
      acc[1][3] = __builtin_amdgcn_mfma_f32_16x16x32_f16(af1, bf3, acc[1][3], 0, 0, 0);
    }
  }

  // epilogue: score[s] = sum_a Wt[a] * tanh(wx + whb)  (C frag: row=fg*4+reg, col=fr)
  float part[2][4];
#pragma unroll
  for (int mi = 0; mi < 2; ++mi)
#pragma unroll
    for (int r = 0; r < 4; ++r) part[mi][r] = 0.f;
#pragma unroll
  for (int ni = 0; ni < 4; ++ni) {
    const int a_idx = wn * 64 + ni * 16 + fr;
    const float wt_a = wt_s[a_idx];
    const float whb_a = whb_s[a_idx];
#pragma unroll
    for (int mi = 0; mi < 2; ++mi)
#pragma unroll
      for (int r = 0; r < 4; ++r)
        part[mi][r] += wt_a * tanh_fast(acc[mi][ni][r] + whb_a);
  }
#pragma unroll
  for (int mask = 1; mask < 16; mask <<= 1) {
#pragma unroll
    for (int mi = 0; mi < 2; ++mi)
#pragma unroll
      for (int r = 0; r < 4; ++r) part[mi][r] += __shfl_xor(part[mi][r], mask, 64);
  }
  if (fr == 0) {
#pragma unroll
    for (int mi = 0; mi < 2; ++mi)
#pragma unroll
      for (int r = 0; r < 4; ++r)
        scorep[wn * BM + wm * 32 + mi * 16 + fg * 4 + r] = part[mi][r];
  }
  __syncthreads();

  // tile-local softmax partial (wave 0 only: tid<64)
  if (tid < BM) {
    float sv = scorep[tid] + scorep[BM + tid] + scorep[2 * BM + tid] + scorep[3 * BM + tid];
    float m = sv;
#pragma unroll
    for (int mask = 1; mask < 64; mask <<= 1) m = fmaxf(m, __shfl_xor(m, mask, 64));
    float p = __expf(sv - m);
    float lsum = p;
#pragma unroll
    for (int mask = 1; mask < 64; mask <<= 1) lsum += __shfl_xor(lsum, mask, 64);
    pbuf[tid] = p;
    if (tid == 0) {
      m_arr[b * NTILES + tile] = m;
      l_arr[b * NTILES + tile] = lsum;
    }
  }
  __syncthreads();

  // acc[d] = sum_r p[r] * x[r][d], from the resident swizzled fp16 tile
  {
    float pacc[8];
#pragma unroll
    for (int j = 0; j < 8; ++j) pacc[j] = 0.f;
#pragma unroll
    for (int r = 0; r < 8; ++r) {
      const int row = wv * 8 + r;
      const float pr = pbuf[row];
      half8 v = *(const half8*)(xs + row * D_DIM + ((lane ^ (row & 7)) * 8));
#pragma unroll
      for (int j = 0; j < 8; ++j) pacc[j] += pr * (float)v[j];
    }
    __syncthreads();                 // all xs reads done before reuse as red buffer
    float* red = (float*)xs;         // 8*512*4 = 16 KiB inside xs
#pragma unroll
    for (int j = 0; j < 8; ++j) red[wv * 512 + lane * 8 + j] = pacc[j];
    __syncthreads();
    float s = 0.f;
#pragma unroll
    for (int w2 = 0; w2 < 8; ++w2) s += red[w2 * 512 + tid];
    acc_arr[((size_t)(b * NTILES + tile)) * D_DIM + tid] = s;
  }
}

__global__ void __launch_bounds__(512)
combine_kernel(const float* __restrict__ m_arr, const float* __restrict__ l_arr,
               const float* __restrict__ acc_arr, float* __restrict__ out) {
  __shared__ float ml[NTILES], ls[NTILES], wl[NTILES];
  const int b = blockIdx.x, tid = threadIdx.x;
  if (tid < NTILES) {
    ml[tid] = m_arr[b * NTILES + tid];
    ls[tid] = l_arr[b * NTILES + tid];
  }
  __syncthreads();
  float M = -1e30f;
  for (int i = 0; i < NTILES; ++i) M = fmaxf(M, ml[i]);
  if (tid < NTILES) wl[tid] = __expf(ml[tid] - M);
  __syncthreads();
  float L = 0.f;
  for (int i = 0; i < NTILES; ++i) L += wl[i] * ls[i];
  float sum = 0.f;
  const size_t base = (size_t)b * NTILES * D_DIM + tid;
  for (int i = 0; i < NTILES; ++i) sum += wl[i] * acc_arr[base + (size_t)i * D_DIM];
  out[b * D_DIM + tid] = sum / L;
}

extern "C" void kernel_launch(void* const* d_in, const int* in_sizes, int n_in,
                              void* d_out, int out_size, void* d_ws, size_t ws_size,
                              hipStream_t stream) {
  const float* x = (const float*)d_in[0];
  const float* h = (const float*)d_in[1];
  const float* Wx = (const float*)d_in[2];
  const float* bx = (const float*)d_in[3];
  const float* Wh = (const float*)d_in[4];
  const float* Wt = (const float*)d_in[5];
  // d_in[6] = bt: unused (softmax shift-invariant)

  char* ws = (char*)d_ws;
  _Float16* Wf = (_Float16*)ws;                               // 262144 B
  float* whb = (float*)(ws + 262144);                         // 65536 B
  float* m_arr = (float*)(ws + 262144 + 65536);               // 32768 B
  float* l_arr = (float*)(ws + 262144 + 65536 + 32768);       // 32768 B
  float* acc_arr = (float*)(ws + 262144 + 65536 + 65536);     // 16.8 MB

  hipFuncSetAttribute(reinterpret_cast<const void*>(paa_main),
                      hipFuncAttributeMaxDynamicSharedMemorySize, SMEM_MAIN);

  hipLaunchKernelGGL(convw_kernel, dim3(64), dim3(256), 0, stream, Wx, Wf);
  hipLaunchKernelGGL(whb_kernel, dim3(B_DIM), dim3(256), 0, stream, h, Wh, bx, whb);
  hipLaunchKernelGGL(paa_main, dim3(NTILES, B_DIM), dim3(512), SMEM_MAIN, stream,
                     x, Wf, whb, Wt, m_arr, l_arr, acc_arr);
  hipLaunchKernelGGL(combine_kernel, dim3(B_DIM), dim3(512), 0, stream,
                     m_arr, l_arr, acc_arr, (float*)d_out);
}

// Round 4
// 405.715 us; speedup vs baseline: 1.6042x; 1.5307x over previous
//
#include <hip/hip_runtime.h>

// PositionAwareAttention: S=8192, B=64, D=512, A=256, all fp32 I/O.
// Fused flash-style: x read from HBM exactly once (1.07 GB).
//   k0: Wx fp32 -> fp16 PACKED in MFMA B-fragment order: tile[ta=a/16][tk=k/32]
//       (1 KB each), elem (fg*16+fr)*8+j -> K-loop B-loads are 64-lane
//       contiguous 1 KB (was 16-way cache-line divergent).
//   k1: whb[b,a] = h[b,:].Wh[a,:] + bx[a] (ws)
//   k2: per (b, 64-row s-tile): wx = x.W^T via f16 MFMA. x staged once into a
//       64 KiB XOR-swizzled fp16 LDS tile (single barrier, barrier-free K-loop);
//       W fragments stream from global (L2) in packed order. Epilogue: tanh +
//       Wt reduce -> tile softmax partial (m, l, acc[512]).
//   k3: combine partials over 128 tiles per b -> out[b,d].
// bt omitted: softmax is shift-invariant.

#define S_DIM 8192
#define B_DIM 64
#define D_DIM 512
#define A_DIM 256
#define BM 64
#define BK 64
#define NCHUNK 8              // D / BK
#define NTILES 128            // S / BM

typedef _Float16 half8 __attribute__((ext_vector_type(8)));
typedef float f32x4 __attribute__((ext_vector_type(4)));

// LDS: xs[64][512] f16 swizzled (65536 B) + scorep[256] + pbuf[64] + whb_s[256] + wt_s[256]
#define SMEM_MAIN (65536 + (256 + 64 + 256 + 256) * 4)

__device__ __forceinline__ float tanh_fast(float x) {
  // tanh(x) = 1 - 2/(exp(2x)+1); exp->inf/0 saturates correctly to +/-1
  float e = __expf(2.0f * x);
  return 1.0f - 2.0f * __builtin_amdgcn_rcpf(e + 1.0f);
}

// Pack Wx (A=256 x K=512 f32) -> fp16 fragment tiles.
// Tile (ta,tk) = 16 a-rows x 32 k; elem (a=ta*16+fr, k=tk*32+fg*8+j) stored at
// Wp[(ta*16+tk)*512 + (fg*16+fr)*8 + j]  => B-frag load = lane*8 contiguous.
__global__ void __launch_bounds__(256)
convw_kernel(const float* __restrict__ Wx, _Float16* __restrict__ Wp) {
  const int idx = (blockIdx.x * 256 + threadIdx.x) * 8;   // 8 consecutive k of one a-row
  const int a = idx >> 9;
  const int k = idx & 511;
  f32x4 va = *(const f32x4*)(Wx + idx);
  f32x4 vb = *(const f32x4*)(Wx + idx + 4);
  half8 hx;
#pragma unroll
  for (int i = 0; i < 4; ++i) { hx[i] = (_Float16)va[i]; hx[4 + i] = (_Float16)vb[i]; }
  const int ta = a >> 4, fr = a & 15;
  const int tk = k >> 5, fg = (k >> 3) & 3;
  *(half8*)(Wp + (ta * 16 + tk) * 512 + (fg * 16 + fr) * 8) = hx;
}

__global__ void __launch_bounds__(256)
whb_kernel(const float* __restrict__ h, const float* __restrict__ Wh,
           const float* __restrict__ bx, float* __restrict__ whb) {
  __shared__ float hs[D_DIM];
  const int b = blockIdx.x, tid = threadIdx.x;
  hs[tid] = h[b * D_DIM + tid];
  hs[tid + 256] = h[b * D_DIM + 256 + tid];
  __syncthreads();
  const int g = tid >> 4, i = tid & 15;  // 16 lanes cooperate on one a-row
  for (int pass = 0; pass < 16; ++pass) {
    const int a = pass * 16 + g;
    const f32x4* wrow = (const f32x4*)(Wh + (size_t)a * D_DIM);
    float dot = 0.f;
#pragma unroll
    for (int k = 0; k < 8; ++k) {
      f32x4 wv = wrow[i + k * 16];
      f32x4 hv = *(const f32x4*)(hs + (i + k * 16) * 4);
      dot += wv[0] * hv[0] + wv[1] * hv[1] + wv[2] * hv[2] + wv[3] * hv[3];
    }
#pragma unroll
    for (int mask = 1; mask < 16; mask <<= 1) dot += __shfl_xor(dot, mask, 64);
    if (i == 0) whb[b * A_DIM + a] = dot + bx[a];
  }
}

__global__ void __launch_bounds__(512, 4)
paa_main(const float* __restrict__ x, const _Float16* __restrict__ Wp,
         const float* __restrict__ whb, const float* __restrict__ Wt,
         float* __restrict__ m_arr, float* __restrict__ l_arr,
         float* __restrict__ acc_arr) {
  extern __shared__ char smem[];
  _Float16* xs = (_Float16*)smem;                 // [64][512] f16, 16B-slot XOR swizzle
  float* scorep = (float*)(smem + 65536);         // [4][BM]
  float* pbuf = scorep + 4 * BM;                  // [BM]
  float* whb_s = pbuf + BM;                       // [A]
  float* wt_s = whb_s + A_DIM;                    // [A]

  const int tid = threadIdx.x;
  const int b = blockIdx.x;                       // b-major: resident blocks read dense x region
  const int tile = blockIdx.y;
  const int s0 = tile * BM;

  if (tid < A_DIM) { whb_s[tid] = whb[b * A_DIM + tid]; wt_s[tid] = Wt[tid]; }

  // x staging map: row xr = tid/8, 8-float segment xj = tid%8
  const int xr = tid >> 3, xj = tid & 7;
  const float* xg = x + (size_t)(s0 + xr) * (B_DIM * D_DIM) + b * D_DIM + xj * 8;
  const int xj_sw = xj ^ (xr & 7);                // swizzled 16B slot within chunk window
  _Float16* xw = xs + xr * D_DIM + xj_sw * 8;

  // ---- one-shot staging: all 16 dwordx4 loads in flight, then convert+write, ONE barrier
  f32x4 xa[NCHUNK], xb[NCHUNK];
#pragma unroll
  for (int c = 0; c < NCHUNK; ++c) {
    const float* p = xg + c * BK;
    xa[c] = *(const f32x4*)(p);
    xb[c] = *(const f32x4*)(p + 4);
  }
#pragma unroll
  for (int c = 0; c < NCHUNK; ++c) {
    half8 hx;
#pragma unroll
    for (int i = 0; i < 4; ++i) { hx[i] = (_Float16)xa[c][i]; hx[4 + i] = (_Float16)xb[c][i]; }
    *(half8*)(xw + c * BK) = hx;
  }
  __syncthreads();

  f32x4 acc[2][4];
#pragma unroll
  for (int i = 0; i < 2; ++i)
#pragma unroll
    for (int j = 0; j < 4; ++j) acc[i][j] = (f32x4){0.f, 0.f, 0.f, 0.f};

  const int lane = tid & 63;
  const int wv = tid >> 6;
  const int wm = wv >> 2, wn = wv & 3;           // wave tile: rows wm*32+.., cols wn*64+..
  const int fr = lane & 15, fg = lane >> 4;
  const int a_row0 = wm * 32 + fr;               // and a_row0+16: same (&7) -> same swizzle key
  const int akey = a_row0 & 7;
  // packed W base for this wave's 64 a-cols: tiles (wn*4 + I)*16 + tk, lane-contiguous
  const _Float16* wp = Wp + wn * 4 * 16 * 512 + lane * 8;

  // ---- K-loop: NO barriers; B-loads are 1 KB lane-contiguous from packed W.
#pragma unroll
  for (int c = 0; c < NCHUNK; ++c) {
#pragma unroll
    for (int kk = 0; kk < 2; ++kk) {
      const int tk = c * 2 + kk;
      const int slot = (c * 8 + kk * 4 + fg) ^ akey;
      half8 af0 = *(const half8*)(xs + a_row0 * D_DIM + slot * 8);
      half8 af1 = *(const half8*)(xs + (a_row0 + 16) * D_DIM + slot * 8);
      half8 bf0 = *(const half8*)(wp + (0 * 16 + tk) * 512);
      half8 bf1 = *(const half8*)(wp + (1 * 16 + tk) * 512);
      half8 bf2 = *(const half8*)(wp + (2 * 16 + tk) * 512);
      half8 bf3 = *(const half8*)(wp + (3 * 16 + tk) * 512);
      acc[0][0] = __builtin_amdgcn_mfma_f32_16x16x32_f16(af0, bf0, acc[0][0], 0, 0, 0);
      acc[0][1] = __builtin_amdgcn_mfma_f32_16x16x32_f16(af0, bf1, acc[0][1], 0, 0, 0);
      acc[0][2] = __builtin_amdgcn_mfma_f32_16x16x32_f16(af0, bf2, acc[0][2], 0, 0, 0);
      acc[0][3] = __builtin_amdgcn_mfma_f32_16x16x32_f16(af0, bf3, acc[0][3], 0, 0, 0);
      acc[1][0] = __builtin_amdgcn_mfma_f32_16x16x32_f16(af1, bf0, acc[1][0], 0, 0, 0);
      acc[1][1] = __builtin_amdgcn_mfma_f32_16x16x32_f16(af1, bf1, acc[1][1], 0, 0, 0);
      acc[1][2] = __builtin_amdgcn_mfma_f32_16x16x32_f16(af1, bf2, acc[1][2], 0, 0, 0);
      acc[1][3] = __builtin_amdgcn_mfma_f32_16x16x32_f16(af1, bf3, acc[1][3], 0, 0, 0);
    }
  }

  // epilogue: score[s] = sum_a Wt[a] * tanh(wx + whb)  (C frag: row=fg*4+reg, col=fr)
  float part[2][4];
#pragma unroll
  for (int mi = 0; mi < 2; ++mi)
#pragma unroll
    for (int r = 0; r < 4; ++r) part[mi][r] = 0.f;
#pragma unroll
  for (int ni = 0; ni < 4; ++ni) {
    const int a_idx = wn * 64 + ni * 16 + fr;
    const float wt_a = wt_s[a_idx];
    const float whb_a = whb_s[a_idx];
#pragma unroll
    for (int mi = 0; mi < 2; ++mi)
#pragma unroll
      for (int r = 0; r < 4; ++r)
        part[mi][r] += wt_a * tanh_fast(acc[mi][ni][r] + whb_a);
  }
#pragma unroll
  for (int mask = 1; mask < 16; mask <<= 1) {
#pragma unroll
    for (int mi = 0; mi < 2; ++mi)
#pragma unroll
      for (int r = 0; r < 4; ++r) part[mi][r] += __shfl_xor(part[mi][r], mask, 64);
  }
  if (fr == 0) {
#pragma unroll
    for (int mi = 0; mi < 2; ++mi)
#pragma unroll
      for (int r = 0; r < 4; ++r)
        scorep[wn * BM + wm * 32 + mi * 16 + fg * 4 + r] = part[mi][r];
  }
  __syncthreads();

  // tile-local softmax partial (wave 0 only: tid<64)
  if (tid < BM) {
    float sv = scorep[tid] + scorep[BM + tid] + scorep[2 * BM + tid] + scorep[3 * BM + tid];
    float m = sv;
#pragma unroll
    for (int mask = 1; mask < 64; mask <<= 1) m = fmaxf(m, __shfl_xor(m, mask, 64));
    float p = __expf(sv - m);
    float lsum = p;
#pragma unroll
    for (int mask = 1; mask < 64; mask <<= 1) lsum += __shfl_xor(lsum, mask, 64);
    pbuf[tid] = p;
    if (tid == 0) {
      m_arr[b * NTILES + tile] = m;
      l_arr[b * NTILES + tile] = lsum;
    }
  }
  __syncthreads();

  // acc[d] = sum_r p[r] * x[r][d], from the resident swizzled fp16 tile
  {
    float pacc[8];
#pragma unroll
    for (int j = 0; j < 8; ++j) pacc[j] = 0.f;
#pragma unroll
    for (int r = 0; r < 8; ++r) {
      const int row = wv * 8 + r;
      const float pr = pbuf[row];
      half8 v = *(const half8*)(xs + row * D_DIM + ((lane ^ (row & 7)) * 8));
#pragma unroll
      for (int j = 0; j < 8; ++j) pacc[j] += pr * (float)v[j];
    }
    __syncthreads();                 // all xs reads done before reuse as red buffer
    float* red = (float*)xs;         // 8*512*4 = 16 KiB inside xs
#pragma unroll
    for (int j = 0; j < 8; ++j) red[wv * 512 + lane * 8 + j] = pacc[j];
    __syncthreads();
    float s = 0.f;
#pragma unroll
    for (int w2 = 0; w2 < 8; ++w2) s += red[w2 * 512 + tid];
    acc_arr[((size_t)(b * NTILES + tile)) * D_DIM + tid] = s;
  }
}

__global__ void __launch_bounds__(512)
combine_kernel(const float* __restrict__ m_arr, const float* __restrict__ l_arr,
               const float* __restrict__ acc_arr, float* __restrict__ out) {
  __shared__ float ml[NTILES], ls[NTILES], wl[NTILES];
  const int b = blockIdx.x, tid = threadIdx.x;
  if (tid < NTILES) {
    ml[tid] = m_arr[b * NTILES + tid];
    ls[tid] = l_arr[b * NTILES + tid];
  }
  __syncthreads();
  float M = -1e30f;
  for (int i = 0; i < NTILES; ++i) M = fmaxf(M, ml[i]);
  if (tid < NTILES) wl[tid] = __expf(ml[tid] - M);
  __syncthreads();
  float L = 0.f;
  for (int i = 0; i < NTILES; ++i) L += wl[i] * ls[i];
  float sum = 0.f;
  const size_t base = (size_t)b * NTILES * D_DIM + tid;
  for (int i = 0; i < NTILES; ++i) sum += wl[i] * acc_arr[base + (size_t)i * D_DIM];
  out[b * D_DIM + tid] = sum / L;
}

extern "C" void kernel_launch(void* const* d_in, const int* in_sizes, int n_in,
                              void* d_out, int out_size, void* d_ws, size_t ws_size,
                              hipStream_t stream) {
  const float* x = (const float*)d_in[0];
  const float* h = (const float*)d_in[1];
  const float* Wx = (const float*)d_in[2];
  const float* bx = (const float*)d_in[3];
  const float* Wh = (const float*)d_in[4];
  const float* Wt = (const float*)d_in[5];
  // d_in[6] = bt: unused (softmax shift-invariant)

  char* ws = (char*)d_ws;
  _Float16* Wp = (_Float16*)ws;                               // 262144 B (packed)
  float* whb = (float*)(ws + 262144);                         // 65536 B
  float* m_arr = (float*)(ws + 262144 + 65536);               // 32768 B
  float* l_arr = (float*)(ws + 262144 + 65536 + 32768);       // 32768 B
  float* acc_arr = (float*)(ws + 262144 + 65536 + 65536);     // 16.8 MB

  hipFuncSetAttribute(reinterpret_cast<const void*>(paa_main),
                      hipFuncAttributeMaxDynamicSharedMemorySize, SMEM_MAIN);

  hipLaunchKernelGGL(convw_kernel, dim3(64), dim3(256), 0, stream, Wx, Wp);
  hipLaunchKernelGGL(whb_kernel, dim3(B_DIM), dim3(256), 0, stream, h, Wh, bx, whb);
  hipLaunchKernelGGL(paa_main, dim3(B_DIM, NTILES), dim3(512), SMEM_MAIN, stream,
                     x, Wp, whb, Wt, m_arr, l_arr, acc_arr);
  hipLaunchKernelGGL(combine_kernel, dim3(B_DIM), dim3(512), 0, stream,
                     m_arr, l_arr, acc_arr, (float*)d_out);
}